// Round 8
// baseline (799.854 us; speedup 1.0000x reference)
//
#include <hip/hip_runtime.h>
#include <hip/hip_bf16.h>
#include <stdint.h>

#define T_TOK 2048
#define H_DIM 1024
#define I_DIM 4096
#define E_NUM 8

#define GBM 256          // gateup M-tile (512 threads, 8 waves 4Mx2N)
#define BM 128           // down M-tile (256 threads, 4 waves 2Mx2N)
#define BN 64
#define BK 32            // K-step (halved: 48KB/24KB LDS -> 3/6 blocks per CU)
#define KS 4             // split-K for down

typedef unsigned short u16;
typedef __bf16 bf16_t;
typedef bf16_t bf16x8 __attribute__((ext_vector_type(8)));
typedef float f32x4 __attribute__((ext_vector_type(4)));

__device__ __forceinline__ u16 f2bf(float f) {
  union { float f; unsigned u; } a; a.f = f;
  unsigned r = a.u + 0x7FFFu + ((a.u >> 16) & 1u);  // RNE
  return (u16)(r >> 16);
}

__device__ __forceinline__ void gload_lds16(const void* g, void* l) {
  __builtin_amdgcn_global_load_lds(
      (const __attribute__((address_space(1))) void*)g,
      (__attribute__((address_space(3))) void*)l, 16, 0, 0);
}

// cheap GELU: tanh-approx via sigmoid, max abs err ~3e-4 (4x headroom vs threshold)
__device__ __forceinline__ float gelu_fast(float g) {
  float y = g * (0.7978845608f + 0.0356774081f * g * g);
  return g / (1.0f + __expf(-2.0f * y));
}

// pack 4 fp32 -> 4 bf16 (one uint2)
__device__ __forceinline__ uint2 pack4(float4 f) {
  union { uint2 u; u16 s[4]; } p;
  p.s[0] = f2bf(f.x); p.s[1] = f2bf(f.y); p.s[2] = f2bf(f.z); p.s[3] = f2bf(f.w);
  return p.u;
}

// ---------------- prep: zero out/counts, convert x -> bf16 ----------------
__global__ __launch_bounds__(256) void k_prep(const float* __restrict__ x,
                                              float* __restrict__ out,
                                              u16* __restrict__ xb,
                                              int* __restrict__ counts) {
  int i = blockIdx.x * 256 + threadIdx.x;
  if (i < E_NUM) counts[i] = 0;
  float4 v = reinterpret_cast<const float4*>(x)[i];
  ushort4 b;
  b.x = f2bf(v.x); b.y = f2bf(v.y); b.z = f2bf(v.z); b.w = f2bf(v.w);
  reinterpret_cast<ushort4*>(xb)[i] = b;
  reinterpret_cast<float4*>(out)[i] = make_float4(0.f, 0.f, 0.f, 0.f);
}

// ---------------- router: fp32 logits, softcap, softmax, top-2 ----------------
__global__ __launch_bounds__(256) void k_router(const float* __restrict__ x,
                                                const float* __restrict__ gw,
                                                int* __restrict__ counts,
                                                int* __restrict__ ids,
                                                float* __restrict__ wts) {
  int gtid = blockIdx.x * 256 + threadIdx.x;
  int t = gtid >> 6;
  int lane = threadIdx.x & 63;
  if (t >= T_TOK) return;
  const float* xr = x + (size_t)t * H_DIM;
  float4 xv[4];
#pragma unroll
  for (int j = 0; j < 4; ++j) xv[j] = reinterpret_cast<const float4*>(xr)[lane + 64 * j];
  float logit[E_NUM];
#pragma unroll
  for (int e = 0; e < E_NUM; ++e) {
    const float4* gr = reinterpret_cast<const float4*>(gw + (size_t)e * H_DIM);
    float s = 0.f;
#pragma unroll
    for (int j = 0; j < 4; ++j) {
      float4 g = gr[lane + 64 * j];
      s += xv[j].x * g.x + xv[j].y * g.y + xv[j].z * g.z + xv[j].w * g.w;
    }
#pragma unroll
    for (int off = 32; off; off >>= 1) s += __shfl_xor(s, off);
    logit[e] = s;
  }
  if (lane == 0) {
    float cap[E_NUM], mx = -1e30f;
#pragma unroll
    for (int e = 0; e < E_NUM; ++e) {
      cap[e] = 30.f * tanhf(logit[e] * (1.f / 30.f));
      mx = fmaxf(mx, cap[e]);
    }
    float p[E_NUM], sum = 0.f;
#pragma unroll
    for (int e = 0; e < E_NUM; ++e) { p[e] = expf(cap[e] - mx); sum += p[e]; }
    int i1 = 0; float p1 = p[0];
#pragma unroll
    for (int e = 1; e < E_NUM; ++e) if (p[e] > p1) { p1 = p[e]; i1 = e; }
    int i2 = -1; float p2 = -1.f;
#pragma unroll
    for (int e = 0; e < E_NUM; ++e) if (e != i1 && p[e] > p2) { p2 = p[e]; i2 = e; }
    float inv = 1.f / sum;
    int s1 = atomicAdd(&counts[i1], 1);
    ids[i1 * T_TOK + s1] = t; wts[i1 * T_TOK + s1] = p1 * inv;
    int s2 = atomicAdd(&counts[i2], 1);
    ids[i2 * T_TOK + s2] = t; wts[i2 * T_TOK + s2] = p2 * inv;
  }
}

__global__ void k_offs(const int* __restrict__ counts, int* __restrict__ offs) {
  if (threadIdx.x == 0) {
    int a = 0;
    for (int e = 0; e < E_NUM; ++e) { offs[e] = a; a += counts[e]; }
  }
}

// ============ gate/up GEMM (BK=32, 48KB LDS -> 3 blocks/CU) ============
// A: gload_lds dbuf (pre-swizzled source). B: fp32 reg-load early, cvt+ds_write
// into other buffer late. ONE __syncthreads per K-step. z==8 slice: w2 cvt.
__global__ __launch_bounds__(512) void k_gateup7(
    const u16* __restrict__ xb, const float* __restrict__ w1g, const float* __restrict__ w1u,
    const float* __restrict__ w2, u16* __restrict__ w2b,
    const int* __restrict__ counts, const int* __restrict__ offs, const int* __restrict__ ids,
    u16* __restrict__ h) {
  if (blockIdx.z == E_NUM) {
    // fused w2 fp32->bf16 conversion (runs concurrently with gateup compute)
    int bid = blockIdx.y * gridDim.x + blockIdx.x;       // 0..511
    const int N4 = E_NUM * H_DIM * I_DIM / 4;
    for (int i = bid * 512 + threadIdx.x; i < N4; i += 512 * 512) {
      float4 v = reinterpret_cast<const float4*>(w2)[i];
      ushort4 b;
      b.x = f2bf(v.x); b.y = f2bf(v.y); b.z = f2bf(v.z); b.w = f2bf(v.w);
      reinterpret_cast<ushort4*>(w2b)[i] = b;
    }
    return;
  }
  const int e = blockIdx.z, mt = blockIdx.x, nt = blockIdx.y;  // mt fastest: w1-tile L2 dedup
  const int cnt = counts[e];
  if (mt * GBM >= cnt) return;
  __shared__ u16 As[2 * GBM * BK];   // 32 KB dbuf
  __shared__ u16 Bg[2 * BN * BK];    // 8 KB dbuf
  __shared__ u16 Bu[2 * BN * BK];    // 8 KB dbuf
  const int tid = threadIdx.x, lane = tid & 63, wid = tid >> 6;
  const int wr = (wid >> 1) * 64, wc = (wid & 1) * 32;
  const int lr = lane & 15, lk = lane >> 4;
  const int i0 = nt * BN;

  // ---- A staging map: granule idx = tid + i*512; row = (tid>>2)+i*128, g = tid&3
  const int ar = tid >> 2, ag = tid & 3;
  const int lgs = ag ^ (ar & 3);             // pre-swizzled source granule (rule #21)
  const u16* asrc[2];
#pragma unroll
  for (int i = 0; i < 2; ++i) {
    int rg = mt * GBM + ar + i * 128;
    if (rg >= cnt) rg = cnt - 1;
    asrc[i] = xb + (size_t)ids[e * T_TOK + rg] * H_DIM + lgs * 8;
  }
  const int abase = wid * 512;               // wave-uniform elem offset (granule=8 elems)

  // ---- B staging map: row = tid>>3 (0..63), 4-float chunk = tid&7
  const int brow = tid >> 3, bc4 = tid & 7;
  const float* gsrc = w1g + (size_t)(e * I_DIM + i0 + brow) * H_DIM + bc4 * 4;
  const float* usrc = w1u + (size_t)(e * I_DIM + i0 + brow) * H_DIM + bc4 * 4;
  const int bofs = brow * BK + (((bc4 >> 1) ^ (brow & 3)) << 3) + (bc4 & 1) * 4;
  float4 RG, RU;

  f32x4 accg[4][2], accu[4][2];
#pragma unroll
  for (int mi = 0; mi < 4; ++mi)
#pragma unroll
    for (int ni = 0; ni < 2; ++ni) { accg[mi][ni] = (f32x4)0.f; accu[mi][ni] = (f32x4)0.f; }

  auto LOADB = [&](int ko) {
    RG = *reinterpret_cast<const float4*>(gsrc + ko);
    RU = *reinterpret_cast<const float4*>(usrc + ko);
  };
  auto WRITEB = [&](int buf) {
    *reinterpret_cast<uint2*>(&Bg[buf * BN * BK + bofs]) = pack4(RG);
    *reinterpret_cast<uint2*>(&Bu[buf * BN * BK + bofs]) = pack4(RU);
  };
  auto STAGE_A = [&](int buf, int ko) {
#pragma unroll
    for (int i = 0; i < 2; ++i)
      gload_lds16(asrc[i] + ko, &As[buf * GBM * BK + i * 4096 + abase]);
  };

  LOADB(0);
  STAGE_A(0, 0);
  WRITEB(0);
  __syncthreads();

  const int NT = H_DIM / BK;   // 32
  for (int kt = 0; kt < NT; ++kt) {
    const int cur = kt & 1;
    if (kt + 1 < NT) {
      LOADB((kt + 1) * BK);               // fp32 loads in flight across compute
      STAGE_A(cur ^ 1, (kt + 1) * BK);
    }
    bf16x8 a[4], bg[2], bu[2];
#pragma unroll
    for (int mi = 0; mi < 4; ++mi) {
      int r = wr + mi * 16 + lr;
      a[mi] = *reinterpret_cast<const bf16x8*>(&As[cur * GBM * BK + r * BK + ((lk ^ (r & 3)) << 3)]);
    }
#pragma unroll
    for (int ni = 0; ni < 2; ++ni) {
      int r = wc + ni * 16 + lr;
      int o = r * BK + ((lk ^ (r & 3)) << 3);
      bg[ni] = *reinterpret_cast<const bf16x8*>(&Bg[cur * BN * BK + o]);
      bu[ni] = *reinterpret_cast<const bf16x8*>(&Bu[cur * BN * BK + o]);
    }
#pragma unroll
    for (int mi = 0; mi < 4; ++mi)
#pragma unroll
      for (int ni = 0; ni < 2; ++ni) {
        accg[mi][ni] = __builtin_amdgcn_mfma_f32_16x16x32_bf16(a[mi], bg[ni], accg[mi][ni], 0, 0, 0);
        accu[mi][ni] = __builtin_amdgcn_mfma_f32_16x16x32_bf16(a[mi], bu[ni], accu[mi][ni], 0, 0, 0);
      }
    if (kt + 1 < NT) WRITEB(cur ^ 1);     // other buffer: no WAR with current readers
    __syncthreads();                      // single barrier per K-step
  }

  const int hbase = offs[e];
#pragma unroll
  for (int mi = 0; mi < 4; ++mi)
#pragma unroll
    for (int rr = 0; rr < 4; ++rr) {
      int grow = mt * GBM + wr + mi * 16 + lk * 4 + rr;   // C/D: row=(lane>>4)*4+reg
      if (grow < cnt) {
        size_t hrow = (size_t)(hbase + grow) * I_DIM;
#pragma unroll
        for (int ni = 0; ni < 2; ++ni) {
          int col = i0 + wc + ni * 16 + lr;               // C/D: col=lane&15
          h[hrow + col] = f2bf(gelu_fast(accg[mi][ni][rr]) * accu[mi][ni][rr]);
        }
      }
    }
}

// ============ down GEMM (BK=32, all-bf16, 24KB LDS -> 6 blocks/CU, split-K) ============
__global__ __launch_bounds__(256) void k_down7(
    const u16* __restrict__ h, const u16* __restrict__ w2b,
    const int* __restrict__ counts, const int* __restrict__ offs, const int* __restrict__ ids,
    const float* __restrict__ wts, float* __restrict__ out) {
  const int e = blockIdx.z, mt = blockIdx.x;
  const int nt = blockIdx.y & 15, ks = blockIdx.y >> 4;
  const int cnt = counts[e];
  if (mt * BM >= cnt) return;
  __shared__ u16 As[2 * BM * BK];   // 16 KB
  __shared__ u16 Bs[2 * BN * BK];   // 8 KB
  const int tid = threadIdx.x, lane = tid & 63, wid = tid >> 6;
  const int wr = (wid >> 1) * 64, wc = (wid & 1) * 32;
  const int lr = lane & 15, lk = lane >> 4;
  const int n0 = nt * BN;
  const int hbase = offs[e];

  const int ar = tid >> 2, ag = tid & 3;
  const int lgs = ag ^ (ar & 3);
  const u16* asrc[2];
#pragma unroll
  for (int i = 0; i < 2; ++i) {
    int rg = mt * BM + ar + i * 64;
    if (rg >= cnt) rg = cnt - 1;
    asrc[i] = h + (size_t)(hbase + rg) * I_DIM + lgs * 8;
  }
  const u16* bsrc = w2b + (size_t)(e * H_DIM + n0 + ar) * I_DIM + lgs * 8;
  const int abase = wid * 512;

  auto STAGE = [&](int buf, int ko) {
#pragma unroll
    for (int i = 0; i < 2; ++i)
      gload_lds16(asrc[i] + ko, &As[buf * BM * BK + i * 2048 + abase]);
    gload_lds16(bsrc + ko, &Bs[buf * BN * BK + abase]);
  };

  f32x4 acc[4][2];
#pragma unroll
  for (int mi = 0; mi < 4; ++mi)
#pragma unroll
    for (int ni = 0; ni < 2; ++ni) acc[mi][ni] = (f32x4)0.f;

  const int KT = I_DIM / BK / KS;           // 32
  const int kbase = ks * KT * BK;
  STAGE(0, kbase);
  __syncthreads();

  for (int kt = 0; kt < KT; ++kt) {
    const int cur = kt & 1;
    if (kt + 1 < KT) STAGE(cur ^ 1, kbase + (kt + 1) * BK);
    bf16x8 a[4], b[2];
#pragma unroll
    for (int mi = 0; mi < 4; ++mi) {
      int r = wr + mi * 16 + lr;
      a[mi] = *reinterpret_cast<const bf16x8*>(&As[cur * BM * BK + r * BK + ((lk ^ (r & 3)) << 3)]);
    }
#pragma unroll
    for (int ni = 0; ni < 2; ++ni) {
      int r = wc + ni * 16 + lr;
      b[ni] = *reinterpret_cast<const bf16x8*>(&Bs[cur * BN * BK + r * BK + ((lk ^ (r & 3)) << 3)]);
    }
#pragma unroll
    for (int mi = 0; mi < 4; ++mi)
#pragma unroll
      for (int ni = 0; ni < 2; ++ni)
        acc[mi][ni] = __builtin_amdgcn_mfma_f32_16x16x32_bf16(a[mi], b[ni], acc[mi][ni], 0, 0, 0);
    __syncthreads();
  }

#pragma unroll
  for (int mi = 0; mi < 4; ++mi)
#pragma unroll
    for (int rr = 0; rr < 4; ++rr) {
      int grow = mt * BM + wr + mi * 16 + lk * 4 + rr;
      if (grow < cnt) {
        int tok = ids[e * T_TOK + grow];
        float w = wts[e * T_TOK + grow];
#pragma unroll
        for (int ni = 0; ni < 2; ++ni) {
          int col = n0 + wc + ni * 16 + lr;
          atomicAdd(&out[(size_t)tok * H_DIM + col], w * acc[mi][ni][rr]);
        }
      }
    }
}

extern "C" void kernel_launch(void* const* d_in, const int* in_sizes, int n_in,
                              void* d_out, int out_size, void* d_ws, size_t ws_size,
                              hipStream_t stream) {
  const float* x   = (const float*)d_in[0];
  const float* gw  = (const float*)d_in[1];
  const float* w1g = (const float*)d_in[2];
  const float* w1u = (const float*)d_in[3];
  const float* w2  = (const float*)d_in[4];
  float* out = (float*)d_out;
  char* ws = (char*)d_ws;

  const size_t MB = 1u << 20;
  const size_t OFF_XB  = 0;                    // 4 MB
  const size_t OFF_H   = 4 * MB;               // 32 MB
  const size_t OFF_W2B = OFF_H + 32 * MB;      // 64 MB
  const size_t OFF_IDS = OFF_W2B + 64 * MB;
  const size_t OFF_WTS = OFF_IDS + (64u << 10);
  const size_t OFF_CNT = OFF_WTS + (64u << 10);

  u16* xb     = (u16*)(ws + OFF_XB);
  u16* h      = (u16*)(ws + OFF_H);
  u16* w2b    = (u16*)(ws + OFF_W2B);
  int* ids    = (int*)(ws + OFF_IDS);
  float* wts  = (float*)(ws + OFF_WTS);
  int* counts = (int*)(ws + OFF_CNT);
  int* offs   = counts + 8;

  k_prep<<<2048, 256, 0, stream>>>(x, out, xb, counts);
  k_router<<<512, 256, 0, stream>>>(x, gw, counts, ids, wts);
  k_offs<<<1, 64, 0, stream>>>(counts, offs);
  // x = mt (fastest: co-running mt blocks share the w1 tile), y = nt, z = expert / w2-cvt
  k_gateup7<<<dim3(T_TOK / GBM, I_DIM / BN, E_NUM + 1), 512, 0, stream>>>(
      xb, w1g, w1u, w2, w2b, counts, offs, ids, h);
  k_down7<<<dim3(T_TOK / BM, (H_DIM / BN) * KS, E_NUM), 256, 0, stream>>>(
      h, w2b, counts, offs, ids, wts, out);
}

// Round 9
// 761.789 us; speedup vs baseline: 1.0500x; 1.0500x over previous
//
#include <hip/hip_runtime.h>
#include <hip/hip_bf16.h>
#include <stdint.h>

#define T_TOK 2048
#define H_DIM 1024
#define I_DIM 4096
#define E_NUM 8

#define BM 128
#define BN 64
#define BK 64
#define KS 4             // split-K for down

typedef unsigned short u16;
typedef __bf16 bf16_t;
typedef bf16_t bf16x8 __attribute__((ext_vector_type(8)));
typedef float f32x4 __attribute__((ext_vector_type(4)));

__device__ __forceinline__ u16 f2bf(float f) {
  union { float f; unsigned u; } a; a.f = f;
  unsigned r = a.u + 0x7FFFu + ((a.u >> 16) & 1u);  // RNE
  return (u16)(r >> 16);
}

__device__ __forceinline__ void gload_lds16(const void* g, void* l) {
  __builtin_amdgcn_global_load_lds(
      (const __attribute__((address_space(1))) void*)g,
      (__attribute__((address_space(3))) void*)l, 16, 0, 0);
}

// cheap GELU: tanh-approx via sigmoid, max abs err ~3e-4 (4x headroom vs threshold)
__device__ __forceinline__ float gelu_fast(float g) {
  float y = g * (0.7978845608f + 0.0356774081f * g * g);
  return g / (1.0f + __expf(-2.0f * y));
}

__device__ __forceinline__ uint4 pack8(float4 f0, float4 f1) {
  union { uint4 u; u16 s[8]; } p;
  p.s[0] = f2bf(f0.x); p.s[1] = f2bf(f0.y); p.s[2] = f2bf(f0.z); p.s[3] = f2bf(f0.w);
  p.s[4] = f2bf(f1.x); p.s[5] = f2bf(f1.y); p.s[6] = f2bf(f1.z); p.s[7] = f2bf(f1.w);
  return p.u;
}

// ---------------- prep: zero out/counts, convert x -> bf16 ----------------
__global__ __launch_bounds__(256) void k_prep(const float* __restrict__ x,
                                              float* __restrict__ out,
                                              u16* __restrict__ xb,
                                              int* __restrict__ counts) {
  int i = blockIdx.x * 256 + threadIdx.x;
  if (i < E_NUM) counts[i] = 0;
  float4 v = reinterpret_cast<const float4*>(x)[i];
  ushort4 b;
  b.x = f2bf(v.x); b.y = f2bf(v.y); b.z = f2bf(v.z); b.w = f2bf(v.w);
  reinterpret_cast<ushort4*>(xb)[i] = b;
  reinterpret_cast<float4*>(out)[i] = make_float4(0.f, 0.f, 0.f, 0.f);
}

// ---------------- streaming fp32 -> bf16 for w1g + w1u ----------------
__global__ __launch_bounds__(256) void k_cvtw1(const float* __restrict__ g,
                                               const float* __restrict__ u,
                                               u16* __restrict__ gb,
                                               u16* __restrict__ ub) {
  const int N8 = E_NUM * I_DIM * H_DIM / 8;   // groups of 8 floats
  for (int i = blockIdx.x * 256 + threadIdx.x; i < N8; i += 2048 * 256) {
    const float4* gp = reinterpret_cast<const float4*>(g) + 2 * (size_t)i;
    const float4* up = reinterpret_cast<const float4*>(u) + 2 * (size_t)i;
    float4 g0 = gp[0], g1 = gp[1];
    float4 u0 = up[0], u1 = up[1];
    reinterpret_cast<uint4*>(gb)[i] = pack8(g0, g1);
    reinterpret_cast<uint4*>(ub)[i] = pack8(u0, u1);
  }
}

// ---------------- router: fp32 logits, softcap, softmax, top-2 ----------------
__global__ __launch_bounds__(256) void k_router(const float* __restrict__ x,
                                                const float* __restrict__ gw,
                                                int* __restrict__ counts,
                                                int* __restrict__ ids,
                                                float* __restrict__ wts) {
  int gtid = blockIdx.x * 256 + threadIdx.x;
  int t = gtid >> 6;
  int lane = threadIdx.x & 63;
  if (t >= T_TOK) return;
  const float* xr = x + (size_t)t * H_DIM;
  float4 xv[4];
#pragma unroll
  for (int j = 0; j < 4; ++j) xv[j] = reinterpret_cast<const float4*>(xr)[lane + 64 * j];
  float logit[E_NUM];
#pragma unroll
  for (int e = 0; e < E_NUM; ++e) {
    const float4* gr = reinterpret_cast<const float4*>(gw + (size_t)e * H_DIM);
    float s = 0.f;
#pragma unroll
    for (int j = 0; j < 4; ++j) {
      float4 g = gr[lane + 64 * j];
      s += xv[j].x * g.x + xv[j].y * g.y + xv[j].z * g.z + xv[j].w * g.w;
    }
#pragma unroll
    for (int off = 32; off; off >>= 1) s += __shfl_xor(s, off);
    logit[e] = s;
  }
  if (lane == 0) {
    float cap[E_NUM], mx = -1e30f;
#pragma unroll
    for (int e = 0; e < E_NUM; ++e) {
      cap[e] = 30.f * tanhf(logit[e] * (1.f / 30.f));
      mx = fmaxf(mx, cap[e]);
    }
    float p[E_NUM], sum = 0.f;
#pragma unroll
    for (int e = 0; e < E_NUM; ++e) { p[e] = expf(cap[e] - mx); sum += p[e]; }
    int i1 = 0; float p1 = p[0];
#pragma unroll
    for (int e = 1; e < E_NUM; ++e) if (p[e] > p1) { p1 = p[e]; i1 = e; }
    int i2 = -1; float p2 = -1.f;
#pragma unroll
    for (int e = 0; e < E_NUM; ++e) if (e != i1 && p[e] > p2) { p2 = p[e]; i2 = e; }
    float inv = 1.f / sum;
    int s1 = atomicAdd(&counts[i1], 1);
    ids[i1 * T_TOK + s1] = t; wts[i1 * T_TOK + s1] = p1 * inv;
    int s2 = atomicAdd(&counts[i2], 1);
    ids[i2 * T_TOK + s2] = t; wts[i2 * T_TOK + s2] = p2 * inv;
  }
}

__global__ void k_offs(const int* __restrict__ counts, int* __restrict__ offs) {
  if (threadIdx.x == 0) {
    int a = 0;
    for (int e = 0; e < E_NUM; ++e) { offs[e] = a; a += counts[e]; }
  }
}

// ===================== gate/up GEMM: m97-faithful single-buffer, bf16 weights =====================
// 32 KB LDS, 2 barriers/K-step, gload_lds(16B) with pre-swizzled sources, swizzled reads.
// z==8 slice streams w2 fp32->bf16 concurrently (consumed only by k_down8).
__global__ __launch_bounds__(256) void k_gateup8(
    const u16* __restrict__ xb, const u16* __restrict__ w1gb, const u16* __restrict__ w1ub,
    const float* __restrict__ w2, u16* __restrict__ w2b,
    const int* __restrict__ counts, const int* __restrict__ offs, const int* __restrict__ ids,
    u16* __restrict__ h) {
  if (blockIdx.z == E_NUM) {
    // fused w2 fp32->bf16 conversion (hidden under gateup compute)
    int bid = blockIdx.y * gridDim.x + blockIdx.x;       // 0..1023
    const int N8 = E_NUM * H_DIM * I_DIM / 8;
    for (int i = bid * 256 + threadIdx.x; i < N8; i += 1024 * 256) {
      const float4* wp = reinterpret_cast<const float4*>(w2) + 2 * (size_t)i;
      float4 f0 = wp[0], f1 = wp[1];
      reinterpret_cast<uint4*>(w2b)[i] = pack8(f0, f1);
    }
    return;
  }
  const int e = blockIdx.z, mt = blockIdx.x, nt = blockIdx.y;   // mt fastest: w1-tile L2 dedup
  const int cnt = counts[e];
  if (mt * BM >= cnt) return;
  __shared__ u16 As[BM * BK];   // 16 KB (single buffer)
  __shared__ u16 Bg[BN * BK];   // 8 KB
  __shared__ u16 Bu[BN * BK];   // 8 KB
  const int tid = threadIdx.x, lane = tid & 63, wid = tid >> 6;
  const int wr = (wid >> 1) * 64, wc = (wid & 1) * 32;
  const int lr = lane & 15, lk = lane >> 4;
  const int i0 = nt * BN;
  const int lrow = lane >> 3;
  const int lgs = (lane & 7) ^ (lrow & 7);   // pre-swizzled source granule (rule #21)
  const int sw = lr & 7;                     // read-side XOR key

  const u16* asrc[4];
#pragma unroll
  for (int i = 0; i < 4; ++i) {
    int rg = mt * BM + wid * 32 + i * 8 + lrow;
    if (rg >= cnt) rg = cnt - 1;
    asrc[i] = xb + (size_t)ids[e * T_TOK + rg] * H_DIM + lgs * 8;
  }
  const u16 *gsrc[2], *usrc[2];
#pragma unroll
  for (int i = 0; i < 2; ++i) {
    size_t o = (size_t)(e * I_DIM + i0 + wid * 16 + i * 8 + lrow) * H_DIM + lgs * 8;
    gsrc[i] = w1gb + o; usrc[i] = w1ub + o;
  }
  u16* aldsb = As + (wid * 32) * BK;   // wave-uniform LDS bases
  u16* gldsb = Bg + (wid * 16) * BK;
  u16* uldsb = Bu + (wid * 16) * BK;

  f32x4 accg[4][2], accu[4][2];
#pragma unroll
  for (int mi = 0; mi < 4; ++mi)
#pragma unroll
    for (int ni = 0; ni < 2; ++ni) { accg[mi][ni] = (f32x4)0.f; accu[mi][ni] = (f32x4)0.f; }

  for (int kt = 0; kt < H_DIM / BK; ++kt) {
    const int ko = kt * BK;
#pragma unroll
    for (int i = 0; i < 4; ++i) gload_lds16(asrc[i] + ko, aldsb + i * 8 * BK);
#pragma unroll
    for (int i = 0; i < 2; ++i) {
      gload_lds16(gsrc[i] + ko, gldsb + i * 8 * BK);
      gload_lds16(usrc[i] + ko, uldsb + i * 8 * BK);
    }
    __syncthreads();
#pragma unroll
    for (int kk = 0; kk < 2; ++kk) {
      const int colg = kk * 4 + lk;
      const int gsw = (colg ^ sw) << 3;
      bf16x8 a[4], bg[2], bu[2];
#pragma unroll
      for (int mi = 0; mi < 4; ++mi)
        a[mi] = *reinterpret_cast<const bf16x8*>(&As[(wr + mi * 16 + lr) * BK + gsw]);
#pragma unroll
      for (int ni = 0; ni < 2; ++ni) {
        bg[ni] = *reinterpret_cast<const bf16x8*>(&Bg[(wc + ni * 16 + lr) * BK + gsw]);
        bu[ni] = *reinterpret_cast<const bf16x8*>(&Bu[(wc + ni * 16 + lr) * BK + gsw]);
      }
#pragma unroll
      for (int mi = 0; mi < 4; ++mi)
#pragma unroll
        for (int ni = 0; ni < 2; ++ni) {
          accg[mi][ni] = __builtin_amdgcn_mfma_f32_16x16x32_bf16(a[mi], bg[ni], accg[mi][ni], 0, 0, 0);
          accu[mi][ni] = __builtin_amdgcn_mfma_f32_16x16x32_bf16(a[mi], bu[ni], accu[mi][ni], 0, 0, 0);
        }
    }
    __syncthreads();
  }

  const int hbase = offs[e];
#pragma unroll
  for (int mi = 0; mi < 4; ++mi)
#pragma unroll
    for (int rr = 0; rr < 4; ++rr) {
      int grow = mt * BM + wr + mi * 16 + lk * 4 + rr;   // C/D: row=(lane>>4)*4+reg
      if (grow < cnt) {
        size_t hrow = (size_t)(hbase + grow) * I_DIM;
#pragma unroll
        for (int ni = 0; ni < 2; ++ni) {
          int col = i0 + wc + ni * 16 + lr;              // C/D: col=lane&15
          h[hrow + col] = f2bf(gelu_fast(accg[mi][ni][rr]) * accu[mi][ni][rr]);
        }
      }
    }
}

// ===================== down GEMM: single-buffer, all-bf16, split-K =====================
__global__ __launch_bounds__(256) void k_down8(
    const u16* __restrict__ h, const u16* __restrict__ w2b,
    const int* __restrict__ counts, const int* __restrict__ offs, const int* __restrict__ ids,
    const float* __restrict__ wts, float* __restrict__ out) {
  const int e = blockIdx.z, mt = blockIdx.x;
  const int nt = blockIdx.y & 15, ks = blockIdx.y >> 4;
  const int cnt = counts[e];
  if (mt * BM >= cnt) return;
  __shared__ u16 As[BM * BK];   // 16 KB
  __shared__ u16 Bs[BN * BK];   // 8 KB
  const int tid = threadIdx.x, lane = tid & 63, wid = tid >> 6;
  const int wr = (wid >> 1) * 64, wc = (wid & 1) * 32;
  const int lr = lane & 15, lk = lane >> 4;
  const int n0 = nt * BN;
  const int hbase = offs[e];
  const int lrow = lane >> 3;
  const int lgs = (lane & 7) ^ (lrow & 7);
  const int sw = lr & 7;

  const u16* asrc[4];
#pragma unroll
  for (int i = 0; i < 4; ++i) {
    int rg = mt * BM + wid * 32 + i * 8 + lrow;
    if (rg >= cnt) rg = cnt - 1;
    asrc[i] = h + (size_t)(hbase + rg) * I_DIM + lgs * 8;
  }
  const u16* bsrc[2];
#pragma unroll
  for (int i = 0; i < 2; ++i)
    bsrc[i] = w2b + (size_t)(e * H_DIM + n0 + wid * 16 + i * 8 + lrow) * I_DIM + lgs * 8;
  u16* aldsb = As + (wid * 32) * BK;
  u16* bldsb = Bs + (wid * 16) * BK;

  f32x4 acc[4][2];
#pragma unroll
  for (int mi = 0; mi < 4; ++mi)
#pragma unroll
    for (int ni = 0; ni < 2; ++ni) acc[mi][ni] = (f32x4)0.f;

  const int KT = I_DIM / BK / KS;           // 16 iters per block
  for (int kt = ks * KT; kt < (ks + 1) * KT; ++kt) {
    const int ko = kt * BK;
#pragma unroll
    for (int i = 0; i < 4; ++i) gload_lds16(asrc[i] + ko, aldsb + i * 8 * BK);
#pragma unroll
    for (int i = 0; i < 2; ++i) gload_lds16(bsrc[i] + ko, bldsb + i * 8 * BK);
    __syncthreads();
#pragma unroll
    for (int kk = 0; kk < 2; ++kk) {
      const int colg = kk * 4 + lk;
      const int gsw = (colg ^ sw) << 3;
      bf16x8 a[4], b[2];
#pragma unroll
      for (int mi = 0; mi < 4; ++mi)
        a[mi] = *reinterpret_cast<const bf16x8*>(&As[(wr + mi * 16 + lr) * BK + gsw]);
#pragma unroll
      for (int ni = 0; ni < 2; ++ni)
        b[ni] = *reinterpret_cast<const bf16x8*>(&Bs[(wc + ni * 16 + lr) * BK + gsw]);
#pragma unroll
      for (int mi = 0; mi < 4; ++mi)
#pragma unroll
        for (int ni = 0; ni < 2; ++ni)
          acc[mi][ni] = __builtin_amdgcn_mfma_f32_16x16x32_bf16(a[mi], b[ni], acc[mi][ni], 0, 0, 0);
    }
    __syncthreads();
  }

#pragma unroll
  for (int mi = 0; mi < 4; ++mi)
#pragma unroll
    for (int rr = 0; rr < 4; ++rr) {
      int grow = mt * BM + wr + mi * 16 + lk * 4 + rr;
      if (grow < cnt) {
        int tok = ids[e * T_TOK + grow];
        float w = wts[e * T_TOK + grow];
#pragma unroll
        for (int ni = 0; ni < 2; ++ni) {
          int col = n0 + wc + ni * 16 + lr;
          atomicAdd(&out[(size_t)tok * H_DIM + col], w * acc[mi][ni][rr]);
        }
      }
    }
}

extern "C" void kernel_launch(void* const* d_in, const int* in_sizes, int n_in,
                              void* d_out, int out_size, void* d_ws, size_t ws_size,
                              hipStream_t stream) {
  const float* x   = (const float*)d_in[0];
  const float* gw  = (const float*)d_in[1];
  const float* w1g = (const float*)d_in[2];
  const float* w1u = (const float*)d_in[3];
  const float* w2  = (const float*)d_in[4];
  float* out = (float*)d_out;
  char* ws = (char*)d_ws;

  const size_t MB = 1u << 20;
  const size_t OFF_XB  = 0;                    // 4 MB
  const size_t OFF_H   = 4 * MB;               // 32 MB
  const size_t OFF_W1G = OFF_H + 32 * MB;      // 64 MB
  const size_t OFF_W1U = OFF_W1G + 64 * MB;    // 64 MB
  const size_t OFF_W2B = OFF_W1U + 64 * MB;    // 64 MB
  const size_t OFF_IDS = OFF_W2B + 64 * MB;
  const size_t OFF_WTS = OFF_IDS + (64u << 10);
  const size_t OFF_CNT = OFF_WTS + (64u << 10);

  u16* xb     = (u16*)(ws + OFF_XB);
  u16* h      = (u16*)(ws + OFF_H);
  u16* w1gb   = (u16*)(ws + OFF_W1G);
  u16* w1ub   = (u16*)(ws + OFF_W1U);
  u16* w2b    = (u16*)(ws + OFF_W2B);
  int* ids    = (int*)(ws + OFF_IDS);
  float* wts  = (float*)(ws + OFF_WTS);
  int* counts = (int*)(ws + OFF_CNT);
  int* offs   = counts + 8;

  k_prep<<<2048, 256, 0, stream>>>(x, out, xb, counts);
  k_router<<<512, 256, 0, stream>>>(x, gw, counts, ids, wts);
  k_offs<<<1, 64, 0, stream>>>(counts, offs);
  k_cvtw1<<<2048, 256, 0, stream>>>(w1g, w1u, w1gb, w1ub);
  // x = mt (fastest: co-running mt blocks share the w1 tile), y = nt, z = expert | w2-cvt
  k_gateup8<<<dim3(T_TOK / BM, I_DIM / BN, E_NUM + 1), 256, 0, stream>>>(
      xb, w1gb, w1ub, w2, w2b, counts, offs, ids, h);
  k_down8<<<dim3(T_TOK / BM, (H_DIM / BN) * KS, E_NUM), 256, 0, stream>>>(
      h, w2b, counts, offs, ids, wts, out);
}

// Round 10
// 372.369 us; speedup vs baseline: 2.1480x; 2.0458x over previous
//
#include <hip/hip_runtime.h>
#include <hip/hip_bf16.h>
#include <stdint.h>

#define T_TOK 2048
#define H_DIM 1024
#define I_DIM 4096
#define E_NUM 8

#define GBM 256          // gateup M-tile (512 threads)
#define BM 128           // down M-tile (256 threads)
#define BN 64
#define BK 64
#define KS 4             // split-K for down

typedef unsigned short u16;
typedef __bf16 bf16_t;
typedef bf16_t bf16x8 __attribute__((ext_vector_type(8)));
typedef float f32x4 __attribute__((ext_vector_type(4)));

__device__ __forceinline__ u16 f2bf(float f) {
  union { float f; unsigned u; } a; a.f = f;
  unsigned r = a.u + 0x7FFFu + ((a.u >> 16) & 1u);  // RNE
  return (u16)(r >> 16);
}

__device__ __forceinline__ void gload_lds16(const void* g, void* l) {
  __builtin_amdgcn_global_load_lds(
      (const __attribute__((address_space(1))) void*)g,
      (__attribute__((address_space(3))) void*)l, 16, 0, 0);
}

// cheap GELU: tanh-approx via sigmoid, max abs err ~3e-4 (4x headroom vs threshold)
__device__ __forceinline__ float gelu_fast(float g) {
  float y = g * (0.7978845608f + 0.0356774081f * g * g);
  return g / (1.0f + __expf(-2.0f * y));
}

__device__ __forceinline__ uint4 pack8(float4 f0, float4 f1) {
  union { uint4 u; u16 s[8]; } p;
  p.s[0] = f2bf(f0.x); p.s[1] = f2bf(f0.y); p.s[2] = f2bf(f0.z); p.s[3] = f2bf(f0.w);
  p.s[4] = f2bf(f1.x); p.s[5] = f2bf(f1.y); p.s[6] = f2bf(f1.z); p.s[7] = f2bf(f1.w);
  return p.u;
}

// ---------------- prep: zero out/counts, convert x -> bf16 ----------------
__global__ __launch_bounds__(256) void k_prep(const float* __restrict__ x,
                                              float* __restrict__ out,
                                              u16* __restrict__ xb,
                                              int* __restrict__ counts) {
  int i = blockIdx.x * 256 + threadIdx.x;
  if (i < E_NUM) counts[i] = 0;
  float4 v = reinterpret_cast<const float4*>(x)[i];
  ushort4 b;
  b.x = f2bf(v.x); b.y = f2bf(v.y); b.z = f2bf(v.z); b.w = f2bf(v.w);
  reinterpret_cast<ushort4*>(xb)[i] = b;
  reinterpret_cast<float4*>(out)[i] = make_float4(0.f, 0.f, 0.f, 0.f);
}

// ---------------- router: fp32 logits, softcap, softmax, top-2 ----------------
__global__ __launch_bounds__(256) void k_router(const float* __restrict__ x,
                                                const float* __restrict__ gw,
                                                int* __restrict__ counts,
                                                int* __restrict__ ids,
                                                float* __restrict__ wts) {
  int gtid = blockIdx.x * 256 + threadIdx.x;
  int t = gtid >> 6;
  int lane = threadIdx.x & 63;
  if (t >= T_TOK) return;
  const float* xr = x + (size_t)t * H_DIM;
  float4 xv[4];
#pragma unroll
  for (int j = 0; j < 4; ++j) xv[j] = reinterpret_cast<const float4*>(xr)[lane + 64 * j];
  float logit[E_NUM];
#pragma unroll
  for (int e = 0; e < E_NUM; ++e) {
    const float4* gr = reinterpret_cast<const float4*>(gw + (size_t)e * H_DIM);
    float s = 0.f;
#pragma unroll
    for (int j = 0; j < 4; ++j) {
      float4 g = gr[lane + 64 * j];
      s += xv[j].x * g.x + xv[j].y * g.y + xv[j].z * g.z + xv[j].w * g.w;
    }
#pragma unroll
    for (int off = 32; off; off >>= 1) s += __shfl_xor(s, off);
    logit[e] = s;
  }
  if (lane == 0) {
    float cap[E_NUM], mx = -1e30f;
#pragma unroll
    for (int e = 0; e < E_NUM; ++e) {
      cap[e] = 30.f * tanhf(logit[e] * (1.f / 30.f));
      mx = fmaxf(mx, cap[e]);
    }
    float p[E_NUM], sum = 0.f;
#pragma unroll
    for (int e = 0; e < E_NUM; ++e) { p[e] = expf(cap[e] - mx); sum += p[e]; }
    int i1 = 0; float p1 = p[0];
#pragma unroll
    for (int e = 1; e < E_NUM; ++e) if (p[e] > p1) { p1 = p[e]; i1 = e; }
    int i2 = -1; float p2 = -1.f;
#pragma unroll
    for (int e = 0; e < E_NUM; ++e) if (e != i1 && p[e] > p2) { p2 = p[e]; i2 = e; }
    float inv = 1.f / sum;
    int s1 = atomicAdd(&counts[i1], 1);
    ids[i1 * T_TOK + s1] = t; wts[i1 * T_TOK + s1] = p1 * inv;
    int s2 = atomicAdd(&counts[i2], 1);
    ids[i2 * T_TOK + s2] = t; wts[i2 * T_TOK + s2] = p2 * inv;
  }
}

__global__ void k_offs(const int* __restrict__ counts, int* __restrict__ offs) {
  if (threadIdx.x == 0) {
    int a = 0;
    for (int e = 0; e < E_NUM; ++e) { offs[e] = a; a += counts[e]; }
  }
}

// ============ gate/up GEMM (round-5 k_gateup4 verbatim): BM=256, 512 thr,
// ============ A gload_lds dbuf, B fp32 reg->cvt dbuf, 1 barrier/K-step;
// ============ z==8 slice streams w2 fp32->bf16 concurrently
__global__ __launch_bounds__(512) void k_gateup4(
    const u16* __restrict__ xb, const float* __restrict__ w1g, const float* __restrict__ w1u,
    const float* __restrict__ w2, u16* __restrict__ w2b,
    const int* __restrict__ counts, const int* __restrict__ offs, const int* __restrict__ ids,
    u16* __restrict__ h) {
  if (blockIdx.z == E_NUM) {
    // -------- fused w2 fp32->bf16 conversion (hidden under gateup compute) --------
    int bid = blockIdx.y * (I_DIM / BN) + blockIdx.x;     // 0..511
    const int N4 = E_NUM * H_DIM * I_DIM / 4;
    for (int i = bid * 512 + threadIdx.x; i < N4; i += 512 * 512) {
      float4 v = reinterpret_cast<const float4*>(w2)[i];
      ushort4 b;
      b.x = f2bf(v.x); b.y = f2bf(v.y); b.z = f2bf(v.z); b.w = f2bf(v.w);
      reinterpret_cast<ushort4*>(w2b)[i] = b;
    }
    return;
  }
  const int e = blockIdx.z, mt = blockIdx.y, nt = blockIdx.x;  // x=nt: B-tile sharers same XCD
  const int cnt = counts[e];
  if (mt * GBM >= cnt) return;
  __shared__ u16 As[2 * GBM * BK];   // 64 KB dbuf (gload_lds dest, linear)
  __shared__ u16 Bg[2 * BN * BK];    // 16 KB dbuf (cvt ds_write dest)
  __shared__ u16 Bu[2 * BN * BK];    // 16 KB
  const int tid = threadIdx.x, lane = tid & 63, wid = tid >> 6;
  const int wr = (wid >> 1) * 64, wc = (wid & 1) * 32;    // 4x2 waves -> 256x64
  const int lr = lane & 15, lk = lane >> 4;
  const int i0 = nt * BN;
  const int lrow = lane >> 3;
  const int lgs = (lane & 7) ^ (lrow & 7);   // pre-swizzled A source granule (rule #21)
  const int sw = lr & 7;                     // read-side XOR key

  const u16* asrc[4];
#pragma unroll
  for (int i = 0; i < 4; ++i) {
    int rg = mt * GBM + wid * 32 + i * 8 + lrow;
    if (rg >= cnt) rg = cnt - 1;
    asrc[i] = xb + (size_t)ids[e * T_TOK + rg] * H_DIM + lgs * 8;
  }
  u16* aldsb = As + (wid * 32) * BK;   // wave-uniform

  const int br = tid >> 3, bc = tid & 7;   // B: 64 rows x 8 granules (8 floats each)
  const float* gsrc = w1g + (size_t)(e * I_DIM + i0 + br) * H_DIM + bc * 8;
  const float* usrc = w1u + (size_t)(e * I_DIM + i0 + br) * H_DIM + bc * 8;
  const int wgo = br * BK + (((bc) ^ (br & 7)) << 3);   // swizzled write offset
  float4 RG0, RG1, RU0, RU1;
  auto LOADB = [&](int ko) {
    RG0 = *reinterpret_cast<const float4*>(gsrc + ko);
    RG1 = *reinterpret_cast<const float4*>(gsrc + ko + 4);
    RU0 = *reinterpret_cast<const float4*>(usrc + ko);
    RU1 = *reinterpret_cast<const float4*>(usrc + ko + 4);
  };
  auto WRITEB = [&](int buf) {
    *reinterpret_cast<uint4*>(&Bg[buf * BN * BK + wgo]) = pack8(RG0, RG1);
    *reinterpret_cast<uint4*>(&Bu[buf * BN * BK + wgo]) = pack8(RU0, RU1);
  };
  auto STAGE_A = [&](int buf, int ko) {
#pragma unroll
    for (int i = 0; i < 4; ++i)
      gload_lds16(asrc[i] + ko, aldsb + buf * GBM * BK + i * 8 * BK);
  };

  f32x4 accg[4][2], accu[4][2];
#pragma unroll
  for (int mi = 0; mi < 4; ++mi)
#pragma unroll
    for (int ni = 0; ni < 2; ++ni) { accg[mi][ni] = (f32x4)0.f; accu[mi][ni] = (f32x4)0.f; }

  // prologue
  LOADB(0);
  STAGE_A(0, 0);
  WRITEB(0);
  __syncthreads();            // drains A stage (vmcnt0) + B ds_writes (lgkmcnt0)

  const int NT = H_DIM / BK;  // 16
  for (int kt = 0; kt < NT; ++kt) {
    const int cur = kt & 1;
    if (kt + 1 < NT) {
      LOADB((kt + 1) * BK);               // fp32 loads in flight across compute (T14)
      STAGE_A(cur ^ 1, (kt + 1) * BK);
    }
#pragma unroll
    for (int kk = 0; kk < 2; ++kk) {
      const int colg = kk * 4 + lk;
      const int gsw = (colg ^ sw) << 3;
      bf16x8 a[4], bg[2], bu[2];
#pragma unroll
      for (int mi = 0; mi < 4; ++mi)
        a[mi] = *reinterpret_cast<const bf16x8*>(&As[cur * GBM * BK + (wr + mi * 16 + lr) * BK + gsw]);
#pragma unroll
      for (int ni = 0; ni < 2; ++ni) {
        bg[ni] = *reinterpret_cast<const bf16x8*>(&Bg[cur * BN * BK + (wc + ni * 16 + lr) * BK + gsw]);
        bu[ni] = *reinterpret_cast<const bf16x8*>(&Bu[cur * BN * BK + (wc + ni * 16 + lr) * BK + gsw]);
      }
#pragma unroll
      for (int mi = 0; mi < 4; ++mi)
#pragma unroll
        for (int ni = 0; ni < 2; ++ni) {
          accg[mi][ni] = __builtin_amdgcn_mfma_f32_16x16x32_bf16(a[mi], bg[ni], accg[mi][ni], 0, 0, 0);
          accu[mi][ni] = __builtin_amdgcn_mfma_f32_16x16x32_bf16(a[mi], bu[ni], accu[mi][ni], 0, 0, 0);
        }
    }
    if (kt + 1 < NT) WRITEB(cur ^ 1);     // other buffer: no WAR with current readers
    __syncthreads();                      // single barrier/K-step
  }

  const int hbase = offs[e];
#pragma unroll
  for (int mi = 0; mi < 4; ++mi)
#pragma unroll
    for (int rr = 0; rr < 4; ++rr) {
      int grow = mt * GBM + wr + mi * 16 + lk * 4 + rr;   // C/D: row=(lane>>4)*4+reg
      if (grow < cnt) {
        size_t hrow = (size_t)(hbase + grow) * I_DIM;
#pragma unroll
        for (int ni = 0; ni < 2; ++ni) {
          int col = i0 + wc + ni * 16 + lr;               // C/D: col=lane&15
          h[hrow + col] = f2bf(gelu_fast(accg[mi][ni][rr]) * accu[mi][ni][rr]);
        }
      }
    }
}

// ============ down GEMM (round-3 structure: dbuf+prefetch+swizzle, all-bf16, split-K) ============
__global__ __launch_bounds__(256) void k_down2(
    const u16* __restrict__ h, const u16* __restrict__ w2b,
    const int* __restrict__ counts, const int* __restrict__ offs, const int* __restrict__ ids,
    const float* __restrict__ wts, float* __restrict__ out) {
  const int e = blockIdx.z, mt = blockIdx.y;
  const int nt = blockIdx.x & 15, ks = blockIdx.x >> 4;
  const int cnt = counts[e];
  if (mt * BM >= cnt) return;
  __shared__ u16 As[2 * BM * BK];   // 32 KB
  __shared__ u16 Bs[2 * BN * BK];   // 16 KB
  const int tid = threadIdx.x, lane = tid & 63, wid = tid >> 6;
  const int wr = (wid >> 1) * 64, wc = (wid & 1) * 32;
  const int lr = lane & 15, lk = lane >> 4;
  const int n0 = nt * BN;
  const int hbase = offs[e];
  const int lrow = lane >> 3;
  const int lgs = (lane & 7) ^ (lrow & 7);
  const int sw = lr & 7;

  const u16* asrc[4];
#pragma unroll
  for (int i = 0; i < 4; ++i) {
    int rg = mt * BM + wid * 32 + i * 8 + lrow;
    if (rg >= cnt) rg = cnt - 1;
    asrc[i] = h + (size_t)(hbase + rg) * I_DIM + lgs * 8;
  }
  const u16* bsrc[2];
#pragma unroll
  for (int i = 0; i < 2; ++i)
    bsrc[i] = w2b + (size_t)(e * H_DIM + n0 + wid * 16 + i * 8 + lrow) * I_DIM + lgs * 8;
  u16* aldsb = As + (wid * 32) * BK;
  u16* bldsb = Bs + (wid * 16) * BK;

  auto STAGE = [&](int buf, int ko) {
#pragma unroll
    for (int i = 0; i < 4; ++i) gload_lds16(asrc[i] + ko, aldsb + buf * BM * BK + i * 8 * BK);
#pragma unroll
    for (int i = 0; i < 2; ++i) gload_lds16(bsrc[i] + ko, bldsb + buf * BN * BK + i * 8 * BK);
  };

  f32x4 acc[4][2];
#pragma unroll
  for (int mi = 0; mi < 4; ++mi)
#pragma unroll
    for (int ni = 0; ni < 2; ++ni) acc[mi][ni] = (f32x4)0.f;

  const int KT = I_DIM / BK / KS;           // 16 iters per block
  const int kbase = ks * KT * BK;
  STAGE(0, kbase);
  __syncthreads();

  for (int kt = 0; kt < KT; ++kt) {
    const int cur = kt & 1;
    if (kt + 1 < KT) STAGE(cur ^ 1, kbase + (kt + 1) * BK);
#pragma unroll
    for (int kk = 0; kk < 2; ++kk) {
      const int colg = kk * 4 + lk;
      const int gsw = (colg ^ sw) << 3;
      bf16x8 a[4], b[2];
#pragma unroll
      for (int mi = 0; mi < 4; ++mi)
        a[mi] = *reinterpret_cast<const bf16x8*>(&As[cur * BM * BK + (wr + mi * 16 + lr) * BK + gsw]);
#pragma unroll
      for (int ni = 0; ni < 2; ++ni)
        b[ni] = *reinterpret_cast<const bf16x8*>(&Bs[cur * BN * BK + (wc + ni * 16 + lr) * BK + gsw]);
#pragma unroll
      for (int mi = 0; mi < 4; ++mi)
#pragma unroll
        for (int ni = 0; ni < 2; ++ni)
          acc[mi][ni] = __builtin_amdgcn_mfma_f32_16x16x32_bf16(a[mi], b[ni], acc[mi][ni], 0, 0, 0);
    }
    __syncthreads();
  }

#pragma unroll
  for (int mi = 0; mi < 4; ++mi)
#pragma unroll
    for (int rr = 0; rr < 4; ++rr) {
      int grow = mt * BM + wr + mi * 16 + lk * 4 + rr;
      if (grow < cnt) {
        int tok = ids[e * T_TOK + grow];
        float w = wts[e * T_TOK + grow];
#pragma unroll
        for (int ni = 0; ni < 2; ++ni) {
          int col = n0 + wc + ni * 16 + lr;
          atomicAdd(&out[(size_t)tok * H_DIM + col], w * acc[mi][ni][rr]);
        }
      }
    }
}

extern "C" void kernel_launch(void* const* d_in, const int* in_sizes, int n_in,
                              void* d_out, int out_size, void* d_ws, size_t ws_size,
                              hipStream_t stream) {
  const float* x   = (const float*)d_in[0];
  const float* gw  = (const float*)d_in[1];
  const float* w1g = (const float*)d_in[2];
  const float* w1u = (const float*)d_in[3];
  const float* w2  = (const float*)d_in[4];
  float* out = (float*)d_out;
  char* ws = (char*)d_ws;

  const size_t MB = 1u << 20;
  const size_t OFF_XB  = 0;                    // 4 MB
  const size_t OFF_H   = 4 * MB;               // 32 MB
  const size_t OFF_W2B = OFF_H + 32 * MB;      // 64 MB
  const size_t OFF_IDS = OFF_W2B + 64 * MB;
  const size_t OFF_WTS = OFF_IDS + (64u << 10);
  const size_t OFF_CNT = OFF_WTS + (64u << 10);

  u16* xb     = (u16*)(ws + OFF_XB);
  u16* h      = (u16*)(ws + OFF_H);
  u16* w2b    = (u16*)(ws + OFF_W2B);
  int* ids    = (int*)(ws + OFF_IDS);
  float* wts  = (float*)(ws + OFF_WTS);
  int* counts = (int*)(ws + OFF_CNT);
  int* offs   = counts + 8;

  k_prep<<<2048, 256, 0, stream>>>(x, out, xb, counts);
  k_router<<<512, 256, 0, stream>>>(x, gw, counts, ids, wts);
  k_offs<<<1, 64, 0, stream>>>(counts, offs);
  // z slices 0..7: experts; z==8: fused w2 fp32->bf16 conversion. x=nt grid (XCD-friendly).
  k_gateup4<<<dim3(I_DIM / BN, T_TOK / GBM, E_NUM + 1), 512, 0, stream>>>(
      xb, w1g, w1u, w2, w2b, counts, offs, ids, h);
  k_down2<<<dim3((H_DIM / BN) * KS, T_TOK / BM, E_NUM), 256, 0, stream>>>(
      h, w2b, counts, offs, ids, wts, out);
}

// Round 11
// 335.861 us; speedup vs baseline: 2.3815x; 1.1087x over previous
//
#include <hip/hip_runtime.h>
#include <hip/hip_bf16.h>
#include <stdint.h>

#define T_TOK 2048
#define H_DIM 1024
#define I_DIM 4096
#define E_NUM 8

#define GBM 256          // gateup M-tile (512 threads)
#define BM 128           // down M-tile (256 threads)
#define BN 64
#define BK 64
#define KS 2             // split-K for down

typedef unsigned short u16;
typedef __bf16 bf16_t;
typedef bf16_t bf16x8 __attribute__((ext_vector_type(8)));
typedef float f32x4 __attribute__((ext_vector_type(4)));

__device__ __forceinline__ u16 f2bf(float f) {
  union { float f; unsigned u; } a; a.f = f;
  unsigned r = a.u + 0x7FFFu + ((a.u >> 16) & 1u);  // RNE
  return (u16)(r >> 16);
}

__device__ __forceinline__ void gload_lds16(const void* g, void* l) {
  __builtin_amdgcn_global_load_lds(
      (const __attribute__((address_space(1))) void*)g,
      (__attribute__((address_space(3))) void*)l, 16, 0, 0);
}

// cheap GELU: tanh-approx via sigmoid, max abs err ~3e-4 (4x headroom vs threshold)
__device__ __forceinline__ float gelu_fast(float g) {
  float y = g * (0.7978845608f + 0.0356774081f * g * g);
  return g / (1.0f + __expf(-2.0f * y));
}

__device__ __forceinline__ uint4 pack8(float4 f0, float4 f1) {
  union { uint4 u; u16 s[8]; } p;
  p.s[0] = f2bf(f0.x); p.s[1] = f2bf(f0.y); p.s[2] = f2bf(f0.z); p.s[3] = f2bf(f0.w);
  p.s[4] = f2bf(f1.x); p.s[5] = f2bf(f1.y); p.s[6] = f2bf(f1.z); p.s[7] = f2bf(f1.w);
  return p.u;
}

// ---------------- prep: zero out/counts, convert x -> bf16 ----------------
__global__ __launch_bounds__(256) void k_prep(const float* __restrict__ x,
                                              float* __restrict__ out,
                                              u16* __restrict__ xb,
                                              int* __restrict__ counts) {
  int i = blockIdx.x * 256 + threadIdx.x;
  if (i < E_NUM) counts[i] = 0;
  float4 v = reinterpret_cast<const float4*>(x)[i];
  ushort4 b;
  b.x = f2bf(v.x); b.y = f2bf(v.y); b.z = f2bf(v.z); b.w = f2bf(v.w);
  reinterpret_cast<ushort4*>(xb)[i] = b;
  reinterpret_cast<float4*>(out)[i] = make_float4(0.f, 0.f, 0.f, 0.f);
}

// ---------------- router: fp32 logits, softcap, softmax, top-2 ----------------
__global__ __launch_bounds__(256) void k_router(const float* __restrict__ x,
                                                const float* __restrict__ gw,
                                                int* __restrict__ counts,
                                                int* __restrict__ ids,
                                                float* __restrict__ wts) {
  int gtid = blockIdx.x * 256 + threadIdx.x;
  int t = gtid >> 6;
  int lane = threadIdx.x & 63;
  if (t >= T_TOK) return;
  const float* xr = x + (size_t)t * H_DIM;
  float4 xv[4];
#pragma unroll
  for (int j = 0; j < 4; ++j) xv[j] = reinterpret_cast<const float4*>(xr)[lane + 64 * j];
  float logit[E_NUM];
#pragma unroll
  for (int e = 0; e < E_NUM; ++e) {
    const float4* gr = reinterpret_cast<const float4*>(gw + (size_t)e * H_DIM);
    float s = 0.f;
#pragma unroll
    for (int j = 0; j < 4; ++j) {
      float4 g = gr[lane + 64 * j];
      s += xv[j].x * g.x + xv[j].y * g.y + xv[j].z * g.z + xv[j].w * g.w;
    }
#pragma unroll
    for (int off = 32; off; off >>= 1) s += __shfl_xor(s, off);
    logit[e] = s;
  }
  if (lane == 0) {
    float cap[E_NUM], mx = -1e30f;
#pragma unroll
    for (int e = 0; e < E_NUM; ++e) {
      cap[e] = 30.f * tanhf(logit[e] * (1.f / 30.f));
      mx = fmaxf(mx, cap[e]);
    }
    float p[E_NUM], sum = 0.f;
#pragma unroll
    for (int e = 0; e < E_NUM; ++e) { p[e] = expf(cap[e] - mx); sum += p[e]; }
    int i1 = 0; float p1 = p[0];
#pragma unroll
    for (int e = 1; e < E_NUM; ++e) if (p[e] > p1) { p1 = p[e]; i1 = e; }
    int i2 = -1; float p2 = -1.f;
#pragma unroll
    for (int e = 0; e < E_NUM; ++e) if (e != i1 && p[e] > p2) { p2 = p[e]; i2 = e; }
    float inv = 1.f / sum;
    int s1 = atomicAdd(&counts[i1], 1);
    ids[i1 * T_TOK + s1] = t; wts[i1 * T_TOK + s1] = p1 * inv;
    int s2 = atomicAdd(&counts[i2], 1);
    ids[i2 * T_TOK + s2] = t; wts[i2 * T_TOK + s2] = p2 * inv;
  }
}

__global__ void k_offs(const int* __restrict__ counts, int* __restrict__ offs) {
  if (threadIdx.x == 0) {
    int a = 0;
    for (int e = 0; e < E_NUM; ++e) { offs[e] = a; a += counts[e]; }
  }
}

// ============ gate/up GEMM: GBM=256, A gload_lds dbuf, B fp32 reg-staged,
// ============ B LDS SINGLE-buffered (80 KB total -> 2 blocks/CU);
// ============ z==8 slice streams w2 fp32->bf16 concurrently
__global__ __launch_bounds__(512) void k_gateup4(
    const u16* __restrict__ xb, const float* __restrict__ w1g, const float* __restrict__ w1u,
    const float* __restrict__ w2, u16* __restrict__ w2b,
    const int* __restrict__ counts, const int* __restrict__ offs, const int* __restrict__ ids,
    u16* __restrict__ h) {
  if (blockIdx.z == E_NUM) {
    // -------- fused w2 fp32->bf16 conversion (hidden under gateup compute) --------
    int bid = blockIdx.y * (I_DIM / BN) + blockIdx.x;     // 0..511
    const int N4 = E_NUM * H_DIM * I_DIM / 4;
    for (int i = bid * 512 + threadIdx.x; i < N4; i += 512 * 512) {
      float4 v = reinterpret_cast<const float4*>(w2)[i];
      ushort4 b;
      b.x = f2bf(v.x); b.y = f2bf(v.y); b.z = f2bf(v.z); b.w = f2bf(v.w);
      reinterpret_cast<ushort4*>(w2b)[i] = b;
    }
    return;
  }
  const int e = blockIdx.z, mt = blockIdx.y, nt = blockIdx.x;  // x=nt: B-tile sharers same XCD
  const int cnt = counts[e];
  if (mt * GBM >= cnt) return;
  __shared__ u16 As[2 * GBM * BK];   // 64 KB dbuf (gload_lds dest, linear)
  __shared__ u16 Bg[BN * BK];        // 8 KB SINGLE buffer (cvt ds_write dest)
  __shared__ u16 Bu[BN * BK];        // 8 KB
  const int tid = threadIdx.x, lane = tid & 63, wid = tid >> 6;
  const int wr = (wid >> 1) * 64, wc = (wid & 1) * 32;    // 4x2 waves -> 256x64
  const int lr = lane & 15, lk = lane >> 4;
  const int i0 = nt * BN;
  const int lrow = lane >> 3;
  const int lgs = (lane & 7) ^ (lrow & 7);   // pre-swizzled A source granule (rule #21)
  const int sw = lr & 7;                     // read-side XOR key

  const u16* asrc[4];
#pragma unroll
  for (int i = 0; i < 4; ++i) {
    int rg = mt * GBM + wid * 32 + i * 8 + lrow;
    if (rg >= cnt) rg = cnt - 1;
    asrc[i] = xb + (size_t)ids[e * T_TOK + rg] * H_DIM + lgs * 8;
  }
  u16* aldsb = As + (wid * 32) * BK;   // wave-uniform

  const int br = tid >> 3, bc = tid & 7;   // B: 64 rows x 8 granules (8 floats each)
  const float* gsrc = w1g + (size_t)(e * I_DIM + i0 + br) * H_DIM + bc * 8;
  const float* usrc = w1u + (size_t)(e * I_DIM + i0 + br) * H_DIM + bc * 8;
  const int wgo = br * BK + (((bc) ^ (br & 7)) << 3);   // swizzled write offset
  float4 RG0, RG1, RU0, RU1;
  auto LOADB = [&](int ko) {
    RG0 = *reinterpret_cast<const float4*>(gsrc + ko);
    RG1 = *reinterpret_cast<const float4*>(gsrc + ko + 4);
    RU0 = *reinterpret_cast<const float4*>(usrc + ko);
    RU1 = *reinterpret_cast<const float4*>(usrc + ko + 4);
  };
  auto WRITEB = [&]() {
    *reinterpret_cast<uint4*>(&Bg[wgo]) = pack8(RG0, RG1);
    *reinterpret_cast<uint4*>(&Bu[wgo]) = pack8(RU0, RU1);
  };
  auto STAGE_A = [&](int buf, int ko) {
#pragma unroll
    for (int i = 0; i < 4; ++i)
      gload_lds16(asrc[i] + ko, aldsb + buf * GBM * BK + i * 8 * BK);
  };

  f32x4 accg[4][2], accu[4][2];
#pragma unroll
  for (int mi = 0; mi < 4; ++mi)
#pragma unroll
    for (int ni = 0; ni < 2; ++ni) { accg[mi][ni] = (f32x4)0.f; accu[mi][ni] = (f32x4)0.f; }

  // prologue: B(0) + A(0)
  LOADB(0);
  STAGE_A(0, 0);
  WRITEB();                   // compiler waits the B reg loads
  __syncthreads();            // drains A(0) stage + B(0) ds_writes

  const int NT = H_DIM / BK;  // 16
  for (int kt = 0; kt < NT; ++kt) {
    const int cur = kt & 1;
    if (kt + 1 < NT) {
      LOADB((kt + 1) * BK);               // fp32 loads in flight across compute (T14)
      STAGE_A(cur ^ 1, (kt + 1) * BK);
    }
#pragma unroll
    for (int kk = 0; kk < 2; ++kk) {
      const int colg = kk * 4 + lk;
      const int gsw = (colg ^ sw) << 3;
      bf16x8 a[4], bg[2], bu[2];
#pragma unroll
      for (int mi = 0; mi < 4; ++mi)
        a[mi] = *reinterpret_cast<const bf16x8*>(&As[cur * GBM * BK + (wr + mi * 16 + lr) * BK + gsw]);
#pragma unroll
      for (int ni = 0; ni < 2; ++ni) {
        bg[ni] = *reinterpret_cast<const bf16x8*>(&Bg[(wc + ni * 16 + lr) * BK + gsw]);
        bu[ni] = *reinterpret_cast<const bf16x8*>(&Bu[(wc + ni * 16 + lr) * BK + gsw]);
      }
#pragma unroll
      for (int mi = 0; mi < 4; ++mi)
#pragma unroll
        for (int ni = 0; ni < 2; ++ni) {
          accg[mi][ni] = __builtin_amdgcn_mfma_f32_16x16x32_bf16(a[mi], bg[ni], accg[mi][ni], 0, 0, 0);
          accu[mi][ni] = __builtin_amdgcn_mfma_f32_16x16x32_bf16(a[mi], bu[ni], accu[mi][ni], 0, 0, 0);
        }
    }
    if (kt + 1 < NT) {
      __syncthreads();        // all reads of B(kt) done; drains this step's loads
      WRITEB();               // overwrite B in place with kt+1
      __syncthreads();        // B(kt+1) + As[cur^1] visible for next step
    }
  }

  const int hbase = offs[e];
#pragma unroll
  for (int mi = 0; mi < 4; ++mi)
#pragma unroll
    for (int rr = 0; rr < 4; ++rr) {
      int grow = mt * GBM + wr + mi * 16 + lk * 4 + rr;   // C/D: row=(lane>>4)*4+reg
      if (grow < cnt) {
        size_t hrow = (size_t)(hbase + grow) * I_DIM;
#pragma unroll
        for (int ni = 0; ni < 2; ++ni) {
          int col = i0 + wc + ni * 16 + lr;               // C/D: col=lane&15
          h[hrow + col] = f2bf(gelu_fast(accg[mi][ni][rr]) * accu[mi][ni][rr]);
        }
      }
    }
}

// ============ down GEMM (dbuf+prefetch+swizzle, all-bf16, split-K KS=2) ============
__global__ __launch_bounds__(256) void k_down2(
    const u16* __restrict__ h, const u16* __restrict__ w2b,
    const int* __restrict__ counts, const int* __restrict__ offs, const int* __restrict__ ids,
    const float* __restrict__ wts, float* __restrict__ out) {
  const int e = blockIdx.z, mt = blockIdx.y;
  const int nt = blockIdx.x & 15, ks = blockIdx.x >> 4;
  const int cnt = counts[e];
  if (mt * BM >= cnt) return;
  __shared__ u16 As[2 * BM * BK];   // 32 KB
  __shared__ u16 Bs[2 * BN * BK];   // 16 KB
  const int tid = threadIdx.x, lane = tid & 63, wid = tid >> 6;
  const int wr = (wid >> 1) * 64, wc = (wid & 1) * 32;
  const int lr = lane & 15, lk = lane >> 4;
  const int n0 = nt * BN;
  const int hbase = offs[e];
  const int lrow = lane >> 3;
  const int lgs = (lane & 7) ^ (lrow & 7);
  const int sw = lr & 7;

  const u16* asrc[4];
#pragma unroll
  for (int i = 0; i < 4; ++i) {
    int rg = mt * BM + wid * 32 + i * 8 + lrow;
    if (rg >= cnt) rg = cnt - 1;
    asrc[i] = h + (size_t)(hbase + rg) * I_DIM + lgs * 8;
  }
  const u16* bsrc[2];
#pragma unroll
  for (int i = 0; i < 2; ++i)
    bsrc[i] = w2b + (size_t)(e * H_DIM + n0 + wid * 16 + i * 8 + lrow) * I_DIM + lgs * 8;
  u16* aldsb = As + (wid * 32) * BK;
  u16* bldsb = Bs + (wid * 16) * BK;

  auto STAGE = [&](int buf, int ko) {
#pragma unroll
    for (int i = 0; i < 4; ++i) gload_lds16(asrc[i] + ko, aldsb + buf * BM * BK + i * 8 * BK);
#pragma unroll
    for (int i = 0; i < 2; ++i) gload_lds16(bsrc[i] + ko, bldsb + buf * BN * BK + i * 8 * BK);
  };

  f32x4 acc[4][2];
#pragma unroll
  for (int mi = 0; mi < 4; ++mi)
#pragma unroll
    for (int ni = 0; ni < 2; ++ni) acc[mi][ni] = (f32x4)0.f;

  const int KT = I_DIM / BK / KS;           // 32 iters per block
  const int kbase = ks * KT * BK;
  STAGE(0, kbase);
  __syncthreads();

  for (int kt = 0; kt < KT; ++kt) {
    const int cur = kt & 1;
    if (kt + 1 < KT) STAGE(cur ^ 1, kbase + (kt + 1) * BK);
#pragma unroll
    for (int kk = 0; kk < 2; ++kk) {
      const int colg = kk * 4 + lk;
      const int gsw = (colg ^ sw) << 3;
      bf16x8 a[4], b[2];
#pragma unroll
      for (int mi = 0; mi < 4; ++mi)
        a[mi] = *reinterpret_cast<const bf16x8*>(&As[cur * BM * BK + (wr + mi * 16 + lr) * BK + gsw]);
#pragma unroll
      for (int ni = 0; ni < 2; ++ni)
        b[ni] = *reinterpret_cast<const bf16x8*>(&Bs[cur * BN * BK + (wc + ni * 16 + lr) * BK + gsw]);
#pragma unroll
      for (int mi = 0; mi < 4; ++mi)
#pragma unroll
        for (int ni = 0; ni < 2; ++ni)
          acc[mi][ni] = __builtin_amdgcn_mfma_f32_16x16x32_bf16(a[mi], b[ni], acc[mi][ni], 0, 0, 0);
    }
    __syncthreads();
  }

#pragma unroll
  for (int mi = 0; mi < 4; ++mi)
#pragma unroll
    for (int rr = 0; rr < 4; ++rr) {
      int grow = mt * BM + wr + mi * 16 + lk * 4 + rr;
      if (grow < cnt) {
        int tok = ids[e * T_TOK + grow];
        float w = wts[e * T_TOK + grow];
#pragma unroll
        for (int ni = 0; ni < 2; ++ni) {
          int col = n0 + wc + ni * 16 + lr;
          atomicAdd(&out[(size_t)tok * H_DIM + col], w * acc[mi][ni][rr]);
        }
      }
    }
}

extern "C" void kernel_launch(void* const* d_in, const int* in_sizes, int n_in,
                              void* d_out, int out_size, void* d_ws, size_t ws_size,
                              hipStream_t stream) {
  const float* x   = (const float*)d_in[0];
  const float* gw  = (const float*)d_in[1];
  const float* w1g = (const float*)d_in[2];
  const float* w1u = (const float*)d_in[3];
  const float* w2  = (const float*)d_in[4];
  float* out = (float*)d_out;
  char* ws = (char*)d_ws;

  const size_t MB = 1u << 20;
  const size_t OFF_XB  = 0;                    // 4 MB
  const size_t OFF_H   = 4 * MB;               // 32 MB
  const size_t OFF_W2B = OFF_H + 32 * MB;      // 64 MB
  const size_t OFF_IDS = OFF_W2B + 64 * MB;
  const size_t OFF_WTS = OFF_IDS + (64u << 10);
  const size_t OFF_CNT = OFF_WTS + (64u << 10);

  u16* xb     = (u16*)(ws + OFF_XB);
  u16* h      = (u16*)(ws + OFF_H);
  u16* w2b    = (u16*)(ws + OFF_W2B);
  int* ids    = (int*)(ws + OFF_IDS);
  float* wts  = (float*)(ws + OFF_WTS);
  int* counts = (int*)(ws + OFF_CNT);
  int* offs   = counts + 8;

  k_prep<<<2048, 256, 0, stream>>>(x, out, xb, counts);
  k_router<<<512, 256, 0, stream>>>(x, gw, counts, ids, wts);
  k_offs<<<1, 64, 0, stream>>>(counts, offs);
  // z slices 0..7: experts; z==8: fused w2 fp32->bf16 conversion. x=nt grid (XCD-friendly).
  k_gateup4<<<dim3(I_DIM / BN, T_TOK / GBM, E_NUM + 1), 512, 0, stream>>>(
      xb, w1g, w1u, w2, w2b, counts, offs, ids, h);
  k_down2<<<dim3((H_DIM / BN) * KS, T_TOK / BM, E_NUM), 256, 0, stream>>>(
      h, w2b, counts, offs, ids, wts, out);
}

// Round 12
// 303.022 us; speedup vs baseline: 2.6396x; 1.1084x over previous
//
#include <hip/hip_runtime.h>
#include <hip/hip_bf16.h>
#include <stdint.h>

#define T_TOK 2048
#define H_DIM 1024
#define I_DIM 4096
#define E_NUM 8

#define GBM 256          // gateup M-tile (512 threads)
#define BM 128           // down M-tile (256 threads)
#define BN 64
#define BK 64
#define KS 2             // split-K for down

typedef unsigned short u16;
typedef __bf16 bf16_t;
typedef bf16_t bf16x8 __attribute__((ext_vector_type(8)));
typedef float f32x4 __attribute__((ext_vector_type(4)));

__device__ __forceinline__ u16 f2bf(float f) {
  union { float f; unsigned u; } a; a.f = f;
  unsigned r = a.u + 0x7FFFu + ((a.u >> 16) & 1u);  // RNE
  return (u16)(r >> 16);
}

__device__ __forceinline__ void gload_lds16(const void* g, void* l) {
  __builtin_amdgcn_global_load_lds(
      (const __attribute__((address_space(1))) void*)g,
      (__attribute__((address_space(3))) void*)l, 16, 0, 0);
}

// cheap GELU: tanh-approx via sigmoid, max abs err ~3e-4 (4x headroom vs threshold)
__device__ __forceinline__ float gelu_fast(float g) {
  float y = g * (0.7978845608f + 0.0356774081f * g * g);
  return g / (1.0f + __expf(-2.0f * y));
}

__device__ __forceinline__ uint4 pack8(float4 f0, float4 f1) {
  union { uint4 u; u16 s[8]; } p;
  p.s[0] = f2bf(f0.x); p.s[1] = f2bf(f0.y); p.s[2] = f2bf(f0.z); p.s[3] = f2bf(f0.w);
  p.s[4] = f2bf(f1.x); p.s[5] = f2bf(f1.y); p.s[6] = f2bf(f1.z); p.s[7] = f2bf(f1.w);
  return p.u;
}

// ---------------- prep: zero out/counts, convert x -> bf16 ----------------
__global__ __launch_bounds__(256) void k_prep(const float* __restrict__ x,
                                              float* __restrict__ out,
                                              u16* __restrict__ xb,
                                              int* __restrict__ counts) {
  int i = blockIdx.x * 256 + threadIdx.x;
  if (i < E_NUM) counts[i] = 0;
  float4 v = reinterpret_cast<const float4*>(x)[i];
  ushort4 b;
  b.x = f2bf(v.x); b.y = f2bf(v.y); b.z = f2bf(v.z); b.w = f2bf(v.w);
  reinterpret_cast<ushort4*>(xb)[i] = b;
  reinterpret_cast<float4*>(out)[i] = make_float4(0.f, 0.f, 0.f, 0.f);
}

// ---------------- router: fp32 logits, softcap, softmax, top-2 ----------------
__global__ __launch_bounds__(256) void k_router(const float* __restrict__ x,
                                                const float* __restrict__ gw,
                                                int* __restrict__ counts,
                                                int* __restrict__ ids,
                                                float* __restrict__ wts) {
  int gtid = blockIdx.x * 256 + threadIdx.x;
  int t = gtid >> 6;
  int lane = threadIdx.x & 63;
  if (t >= T_TOK) return;
  const float* xr = x + (size_t)t * H_DIM;
  float4 xv[4];
#pragma unroll
  for (int j = 0; j < 4; ++j) xv[j] = reinterpret_cast<const float4*>(xr)[lane + 64 * j];
  float logit[E_NUM];
#pragma unroll
  for (int e = 0; e < E_NUM; ++e) {
    const float4* gr = reinterpret_cast<const float4*>(gw + (size_t)e * H_DIM);
    float s = 0.f;
#pragma unroll
    for (int j = 0; j < 4; ++j) {
      float4 g = gr[lane + 64 * j];
      s += xv[j].x * g.x + xv[j].y * g.y + xv[j].z * g.z + xv[j].w * g.w;
    }
#pragma unroll
    for (int off = 32; off; off >>= 1) s += __shfl_xor(s, off);
    logit[e] = s;
  }
  if (lane == 0) {
    float cap[E_NUM], mx = -1e30f;
#pragma unroll
    for (int e = 0; e < E_NUM; ++e) {
      cap[e] = 30.f * tanhf(logit[e] * (1.f / 30.f));
      mx = fmaxf(mx, cap[e]);
    }
    float p[E_NUM], sum = 0.f;
#pragma unroll
    for (int e = 0; e < E_NUM; ++e) { p[e] = expf(cap[e] - mx); sum += p[e]; }
    int i1 = 0; float p1 = p[0];
#pragma unroll
    for (int e = 1; e < E_NUM; ++e) if (p[e] > p1) { p1 = p[e]; i1 = e; }
    int i2 = -1; float p2 = -1.f;
#pragma unroll
    for (int e = 0; e < E_NUM; ++e) if (e != i1 && p[e] > p2) { p2 = p[e]; i2 = e; }
    float inv = 1.f / sum;
    int s1 = atomicAdd(&counts[i1], 1);
    ids[i1 * T_TOK + s1] = t; wts[i1 * T_TOK + s1] = p1 * inv;
    int s2 = atomicAdd(&counts[i2], 1);
    ids[i2 * T_TOK + s2] = t; wts[i2 * T_TOK + s2] = p2 * inv;
  }
}

__global__ void k_offs(const int* __restrict__ counts, int* __restrict__ offs) {
  if (threadIdx.x == 0) {
    int a = 0;
    for (int e = 0; e < E_NUM; ++e) { offs[e] = a; a += counts[e]; }
  }
}

// ============ gate/up GEMM: GBM=256, A gload_lds dbuf, B fp32 reg-staged,
// ============ B LDS single-buffered (80 KB -> 2 blocks/CU). No cvt slice.
__global__ __launch_bounds__(512) void k_gateup4(
    const u16* __restrict__ xb, const float* __restrict__ w1g, const float* __restrict__ w1u,
    const int* __restrict__ counts, const int* __restrict__ offs, const int* __restrict__ ids,
    u16* __restrict__ h) {
  const int e = blockIdx.z, mt = blockIdx.y, nt = blockIdx.x;  // x=nt: B-tile sharers same XCD
  const int cnt = counts[e];
  if (mt * GBM >= cnt) return;
  __shared__ u16 As[2 * GBM * BK];   // 64 KB dbuf (gload_lds dest, linear)
  __shared__ u16 Bg[BN * BK];        // 8 KB single buffer (cvt ds_write dest)
  __shared__ u16 Bu[BN * BK];        // 8 KB
  const int tid = threadIdx.x, lane = tid & 63, wid = tid >> 6;
  const int wr = (wid >> 1) * 64, wc = (wid & 1) * 32;    // 4x2 waves -> 256x64
  const int lr = lane & 15, lk = lane >> 4;
  const int i0 = nt * BN;
  const int lrow = lane >> 3;
  const int lgs = (lane & 7) ^ (lrow & 7);   // pre-swizzled A source granule (rule #21)
  const int sw = lr & 7;                     // read-side XOR key

  const u16* asrc[4];
#pragma unroll
  for (int i = 0; i < 4; ++i) {
    int rg = mt * GBM + wid * 32 + i * 8 + lrow;
    if (rg >= cnt) rg = cnt - 1;
    asrc[i] = xb + (size_t)ids[e * T_TOK + rg] * H_DIM + lgs * 8;
  }
  u16* aldsb = As + (wid * 32) * BK;   // wave-uniform

  const int br = tid >> 3, bc = tid & 7;   // B: 64 rows x 8 granules (8 floats each)
  const float* gsrc = w1g + (size_t)(e * I_DIM + i0 + br) * H_DIM + bc * 8;
  const float* usrc = w1u + (size_t)(e * I_DIM + i0 + br) * H_DIM + bc * 8;
  const int wgo = br * BK + (((bc) ^ (br & 7)) << 3);   // swizzled write offset
  float4 RG0, RG1, RU0, RU1;
  auto LOADB = [&](int ko) {
    RG0 = *reinterpret_cast<const float4*>(gsrc + ko);
    RG1 = *reinterpret_cast<const float4*>(gsrc + ko + 4);
    RU0 = *reinterpret_cast<const float4*>(usrc + ko);
    RU1 = *reinterpret_cast<const float4*>(usrc + ko + 4);
  };
  auto WRITEB = [&]() {
    *reinterpret_cast<uint4*>(&Bg[wgo]) = pack8(RG0, RG1);
    *reinterpret_cast<uint4*>(&Bu[wgo]) = pack8(RU0, RU1);
  };
  auto STAGE_A = [&](int buf, int ko) {
#pragma unroll
    for (int i = 0; i < 4; ++i)
      gload_lds16(asrc[i] + ko, aldsb + buf * GBM * BK + i * 8 * BK);
  };

  f32x4 accg[4][2], accu[4][2];
#pragma unroll
  for (int mi = 0; mi < 4; ++mi)
#pragma unroll
    for (int ni = 0; ni < 2; ++ni) { accg[mi][ni] = (f32x4)0.f; accu[mi][ni] = (f32x4)0.f; }

  // prologue: B(0) + A(0)
  LOADB(0);
  STAGE_A(0, 0);
  WRITEB();
  __syncthreads();            // drains A(0) stage + B(0) ds_writes

  const int NT = H_DIM / BK;  // 16
  for (int kt = 0; kt < NT; ++kt) {
    const int cur = kt & 1;
    if (kt + 1 < NT) {
      LOADB((kt + 1) * BK);               // fp32 loads in flight across compute (T14)
      STAGE_A(cur ^ 1, (kt + 1) * BK);
    }
#pragma unroll
    for (int kk = 0; kk < 2; ++kk) {
      const int colg = kk * 4 + lk;
      const int gsw = (colg ^ sw) << 3;
      bf16x8 a[4], bg[2], bu[2];
#pragma unroll
      for (int mi = 0; mi < 4; ++mi)
        a[mi] = *reinterpret_cast<const bf16x8*>(&As[cur * GBM * BK + (wr + mi * 16 + lr) * BK + gsw]);
#pragma unroll
      for (int ni = 0; ni < 2; ++ni) {
        bg[ni] = *reinterpret_cast<const bf16x8*>(&Bg[(wc + ni * 16 + lr) * BK + gsw]);
        bu[ni] = *reinterpret_cast<const bf16x8*>(&Bu[(wc + ni * 16 + lr) * BK + gsw]);
      }
#pragma unroll
      for (int mi = 0; mi < 4; ++mi)
#pragma unroll
        for (int ni = 0; ni < 2; ++ni) {
          accg[mi][ni] = __builtin_amdgcn_mfma_f32_16x16x32_bf16(a[mi], bg[ni], accg[mi][ni], 0, 0, 0);
          accu[mi][ni] = __builtin_amdgcn_mfma_f32_16x16x32_bf16(a[mi], bu[ni], accu[mi][ni], 0, 0, 0);
        }
    }
    if (kt + 1 < NT) {
      __syncthreads();        // all reads of B(kt) done; drains this step's loads
      WRITEB();               // overwrite B in place with kt+1
      __syncthreads();        // B(kt+1) + As[cur^1] visible
    }
  }

  const int hbase = offs[e];
#pragma unroll
  for (int mi = 0; mi < 4; ++mi)
#pragma unroll
    for (int rr = 0; rr < 4; ++rr) {
      int grow = mt * GBM + wr + mi * 16 + lk * 4 + rr;   // C/D: row=(lane>>4)*4+reg
      if (grow < cnt) {
        size_t hrow = (size_t)(hbase + grow) * I_DIM;
#pragma unroll
        for (int ni = 0; ni < 2; ++ni) {
          int col = i0 + wc + ni * 16 + lr;               // C/D: col=lane&15
          h[hrow + col] = f2bf(gelu_fast(accg[mi][ni][rr]) * accu[mi][ni][rr]);
        }
      }
    }
}

// ============ down GEMM: A=h gload_lds dbuf, B=w2 fp32 reg-staged single-buffer,
// ============ 40 KB LDS -> 4 blocks/CU, split-K KS=2, atomic scatter-add ============
__global__ __launch_bounds__(256) void k_down9(
    const u16* __restrict__ h, const float* __restrict__ w2,
    const int* __restrict__ counts, const int* __restrict__ offs, const int* __restrict__ ids,
    const float* __restrict__ wts, float* __restrict__ out) {
  const int e = blockIdx.z, mt = blockIdx.y;
  const int nt = blockIdx.x & 15, ks = blockIdx.x >> 4;
  const int cnt = counts[e];
  if (mt * BM >= cnt) return;
  __shared__ u16 As[2 * BM * BK];   // 32 KB dbuf
  __shared__ u16 Bs[BN * BK];       // 8 KB single buffer
  const int tid = threadIdx.x, lane = tid & 63, wid = tid >> 6;
  const int wr = (wid >> 1) * 64, wc = (wid & 1) * 32;
  const int lr = lane & 15, lk = lane >> 4;
  const int n0 = nt * BN;
  const int hbase = offs[e];
  const int lrow = lane >> 3;
  const int lgs = (lane & 7) ^ (lrow & 7);
  const int sw = lr & 7;

  const u16* asrc[4];
#pragma unroll
  for (int i = 0; i < 4; ++i) {
    int rg = mt * BM + wid * 32 + i * 8 + lrow;
    if (rg >= cnt) rg = cnt - 1;
    asrc[i] = h + (size_t)(hbase + rg) * I_DIM + lgs * 8;
  }
  u16* aldsb = As + (wid * 32) * BK;

  // B: w2 fp32, row = tid>>2 (0..63), chunk = (tid&3)*16 floats (64B/thread)
  const int brw = tid >> 2, bc4 = tid & 3;
  const float* bsrc = w2 + (size_t)(e * H_DIM + n0 + brw) * I_DIM + bc4 * 16;
  const int wg0 = brw * BK + (((bc4 * 2) ^ (brw & 7)) << 3);
  const int wg1 = brw * BK + (((bc4 * 2 + 1) ^ (brw & 7)) << 3);
  float4 RB0, RB1, RB2, RB3;
  auto LOADB = [&](int ko) {
    RB0 = *reinterpret_cast<const float4*>(bsrc + ko);
    RB1 = *reinterpret_cast<const float4*>(bsrc + ko + 4);
    RB2 = *reinterpret_cast<const float4*>(bsrc + ko + 8);
    RB3 = *reinterpret_cast<const float4*>(bsrc + ko + 12);
  };
  auto WRITEB = [&]() {
    *reinterpret_cast<uint4*>(&Bs[wg0]) = pack8(RB0, RB1);
    *reinterpret_cast<uint4*>(&Bs[wg1]) = pack8(RB2, RB3);
  };
  auto STAGE_A = [&](int buf, int ko) {
#pragma unroll
    for (int i = 0; i < 4; ++i)
      gload_lds16(asrc[i] + ko, aldsb + buf * BM * BK + i * 8 * BK);
  };

  f32x4 acc[4][2];
#pragma unroll
  for (int mi = 0; mi < 4; ++mi)
#pragma unroll
    for (int ni = 0; ni < 2; ++ni) acc[mi][ni] = (f32x4)0.f;

  const int KT = I_DIM / BK / KS;           // 32 iters per block
  const int kbase = ks * KT * BK;
  LOADB(kbase);
  STAGE_A(0, kbase);
  WRITEB();
  __syncthreads();

  for (int kt = 0; kt < KT; ++kt) {
    const int cur = kt & 1;
    if (kt + 1 < KT) {
      LOADB(kbase + (kt + 1) * BK);
      STAGE_A(cur ^ 1, kbase + (kt + 1) * BK);
    }
#pragma unroll
    for (int kk = 0; kk < 2; ++kk) {
      const int colg = kk * 4 + lk;
      const int gsw = (colg ^ sw) << 3;
      bf16x8 a[4], b[2];
#pragma unroll
      for (int mi = 0; mi < 4; ++mi)
        a[mi] = *reinterpret_cast<const bf16x8*>(&As[cur * BM * BK + (wr + mi * 16 + lr) * BK + gsw]);
#pragma unroll
      for (int ni = 0; ni < 2; ++ni)
        b[ni] = *reinterpret_cast<const bf16x8*>(&Bs[(wc + ni * 16 + lr) * BK + gsw]);
#pragma unroll
      for (int mi = 0; mi < 4; ++mi)
#pragma unroll
        for (int ni = 0; ni < 2; ++ni)
          acc[mi][ni] = __builtin_amdgcn_mfma_f32_16x16x32_bf16(a[mi], b[ni], acc[mi][ni], 0, 0, 0);
    }
    if (kt + 1 < KT) {
      __syncthreads();        // reads of Bs done; drains this step's loads
      WRITEB();
      __syncthreads();
    }
  }

#pragma unroll
  for (int mi = 0; mi < 4; ++mi)
#pragma unroll
    for (int rr = 0; rr < 4; ++rr) {
      int grow = mt * BM + wr + mi * 16 + lk * 4 + rr;
      if (grow < cnt) {
        int tok = ids[e * T_TOK + grow];
        float w = wts[e * T_TOK + grow];
#pragma unroll
        for (int ni = 0; ni < 2; ++ni) {
          int col = n0 + wc + ni * 16 + lr;
          atomicAdd(&out[(size_t)tok * H_DIM + col], w * acc[mi][ni][rr]);
        }
      }
    }
}

extern "C" void kernel_launch(void* const* d_in, const int* in_sizes, int n_in,
                              void* d_out, int out_size, void* d_ws, size_t ws_size,
                              hipStream_t stream) {
  const float* x   = (const float*)d_in[0];
  const float* gw  = (const float*)d_in[1];
  const float* w1g = (const float*)d_in[2];
  const float* w1u = (const float*)d_in[3];
  const float* w2  = (const float*)d_in[4];
  float* out = (float*)d_out;
  char* ws = (char*)d_ws;

  const size_t MB = 1u << 20;
  const size_t OFF_XB  = 0;                    // 4 MB
  const size_t OFF_H   = 4 * MB;               // 32 MB
  const size_t OFF_IDS = OFF_H + 32 * MB;
  const size_t OFF_WTS = OFF_IDS + (64u << 10);
  const size_t OFF_CNT = OFF_WTS + (64u << 10);

  u16* xb     = (u16*)(ws + OFF_XB);
  u16* h      = (u16*)(ws + OFF_H);
  int* ids    = (int*)(ws + OFF_IDS);
  float* wts  = (float*)(ws + OFF_WTS);
  int* counts = (int*)(ws + OFF_CNT);
  int* offs   = counts + 8;

  k_prep<<<2048, 256, 0, stream>>>(x, out, xb, counts);
  k_router<<<512, 256, 0, stream>>>(x, gw, counts, ids, wts);
  k_offs<<<1, 64, 0, stream>>>(counts, offs);
  k_gateup4<<<dim3(I_DIM / BN, T_TOK / GBM, E_NUM), 512, 0, stream>>>(
      xb, w1g, w1u, counts, offs, ids, h);
  k_down9<<<dim3((H_DIM / BN) * KS, T_TOK / BM, E_NUM), 256, 0, stream>>>(
      h, w2, counts, offs, ids, wts, out);
}